// Round 21
// baseline (169.936 us; speedup 1.0000x reference)
//
#include <hip/hip_runtime.h>

// Self-attention: x(4,2048,1024) fp32; W_Q/K/V/O (1024,1024) fp32.
// QKV GEMM: 512-thr 256x128 blocks (R20-validated: -25% stage issue, -50%
// barriers/MFMA, 670 TF) + out-proj with the SAME geometry + flash attention
// (R17-frozen: fixed-zero-max softmax, l-via-ones-MFMA, XOR-swizzled LDS).

#define B_  4
#define S_  2048
#define D_  1024
#define H_  16
#define HD_ 64

typedef __attribute__((ext_vector_type(8))) short bf16x8;
typedef __attribute__((ext_vector_type(4))) float f32x4;

#define MFMA16 __builtin_amdgcn_mfma_f32_16x16x32_bf16

__device__ __forceinline__ unsigned short f2b(float f) {
  unsigned u = __builtin_bit_cast(unsigned, f);
  unsigned r = (u + 0x7FFFu + ((u >> 16) & 1u)) >> 16;  // RNE
  return (unsigned short)r;
}

__device__ __forceinline__ unsigned cvtpk(float lo, float hi) {
  unsigned r;
  asm("v_cvt_pk_bf16_f32 %0, %1, %2" : "=v"(r) : "v"(lo), "v"(hi));
  return r;
}

// async global->LDS, 16B per lane. LDS dest must be wave-uniform base.
__device__ __forceinline__ void gll16(const void* g, const void* l) {
  __builtin_amdgcn_global_load_lds(
      (const __attribute__((address_space(1))) unsigned int*)g,
      (__attribute__((address_space(3))) unsigned int*)l, 16, 0, 0);
}

// ---------------- fp32 -> bf16 conversion (all 5 tensors, 1 launch) -------
__global__ __launch_bounds__(256) void cvt_all(
    const float4* __restrict__ x,  const float4* __restrict__ wq,
    const float4* __restrict__ wk, const float4* __restrict__ wv,
    const float4* __restrict__ wo,
    ushort4* __restrict__ xb,  ushort4* __restrict__ wqb,
    ushort4* __restrict__ wkb, ushort4* __restrict__ wvb,
    ushort4* __restrict__ wob)
{
  const int y = blockIdx.y;
  const float4* in; ushort4* out;
  if (y < 8)       { in = x  + (size_t)y * 262144; out = xb  + (size_t)y * 262144; }
  else if (y == 8) { in = wq; out = wqb; }
  else if (y == 9) { in = wk; out = wkb; }
  else if (y == 10){ in = wv; out = wvb; }
  else             { in = wo; out = wob; }
  int i = blockIdx.x * 256 + threadIdx.x;
  float4 v = in[i];
  ushort4 o;
  o.x = f2b(v.x); o.y = f2b(v.y); o.z = f2b(v.z); o.w = f2b(v.w);
  out[i] = o;
}

// ---------------- 512-thr 256x128 GEMM core (R20-validated) ----------------
// 8 waves: wm = w>>1 (4 x 64 rows), wn = w&1 (2 x 64 cols), 64x64 wave tile.
// T2 slot-swizzle: src slot ^= (lane>>3)&3 (== (row>>1)&3; wave-row base
// contributes 0); read slot = g ^ ((r16>>1)&3). LDS 48KB.
#define QSTG(BF, K0) { \
    gll16(A + (size_t)(arow +       w*16 + srow)*1024 + (K0) + scol, &As[BF][        w*512]); \
    gll16(A + (size_t)(arow + 128 + w*16 + srow)*1024 + (K0) + scol, &As[BF][4096 + w*512]); \
    gll16(W + (size_t)(brow +       w*16 + srow)*1024 + (K0) + scol, &Bs[BF][        w*512]); }

#define QSTEP(BF, SW) { \
    bf16x8 af[4], bfr[4]; \
    _Pragma("unroll") for (int i = 0; i < 4; ++i) \
      af[i]  = *(const bf16x8*)(&As[BF][(wm*64 + i*16 + r16)*32 + rslot]); \
    _Pragma("unroll") for (int i = 0; i < 4; ++i) \
      bfr[i] = *(const bf16x8*)(&Bs[BF][(wn*64 + i*16 + r16)*32 + rslot]); \
    _Pragma("unroll") for (int i = 0; i < 4; ++i) \
      _Pragma("unroll") for (int j = 0; j < 4; ++j) \
        acc[i][j] = (SW) ? MFMA16(bfr[j], af[i], acc[i][j], 0, 0, 0) \
                         : MFMA16(af[i], bfr[j], acc[i][j], 0, 0, 0); }

#define QLOOP(SW) \
  for (int kt = 0; kt < 32; kt += 2) { \
    __syncthreads(); \
    QSTG(1, (kt + 1) * 32); \
    QSTEP(0, SW); \
    __syncthreads(); \
    if (kt + 2 < 32) QSTG(0, (kt + 2) * 32); \
    QSTEP(1, SW); \
  }

// ---------------- fused QKV GEMM ------------------------------------------
// A[8192][1024] x W3[3072][1024]^T. 768 blocks (32 bm2 x 24 bn). bn<8 -> Q
// (swapped, scaled); bn<16 -> K (swapped); else V (normal -> V^T).
__global__ __launch_bounds__(512) void gemm_qkv(
    const unsigned short* __restrict__ A,
    const unsigned short* __restrict__ W,
    unsigned short* __restrict__ OQ,
    unsigned short* __restrict__ OK,
    unsigned short* __restrict__ OV)
{
  const int tid  = threadIdx.x;
  const int lane = tid & 63;
  const int w    = tid >> 6;          // 0..7
  const int wm   = w >> 1, wn = w & 1;
  const int r16  = lane & 15, g = lane >> 4;

  // XCD-grouping swizzle over 768 blocks: XCD x owns bm2 in {4x..4x+3}.
  const int orig = blockIdx.x;
  const int bm2  = (orig & 7) * 4 + ((orig >> 3) & 3);
  const int bn   = orig >> 5;                        // 0..23

  __shared__ unsigned short As[2][8192];   // 256x32
  __shared__ unsigned short Bs[2][4096];   // 128x32

  const int arow = bm2 * 256, brow = bn * 128;
  const int srow = lane >> 2;
  const int scol  = ((lane & 3) ^ ((lane >> 3) & 3)) * 8;
  const int rslot = (g ^ ((r16 >> 1) & 3)) * 8;

  f32x4 acc[4][4] = {};
  const bool vblk = (bn >= 16);
  QSTG(0, 0);
  if (!vblk) { QLOOP(true) } else { QLOOP(false) }

  if (!vblk) {              // Q or K (swapped): lane holds 4 consecutive features
    unsigned short* Od = (bn < 8) ? OQ : OK;
    const float scl = (bn < 8) ? 0.18033688f : 1.0f;   // 0.125*log2(e)
    #pragma unroll
    for (int i = 0; i < 4; ++i)
      #pragma unroll
      for (int j = 0; j < 4; ++j) {
        int t = arow + wm*64 + i*16 + r16;
        int f = (brow & 1023) + wn*64 + j*16 + g*4;
        int b = t >> 11, s = t & 2047, h = f >> 6, hd = f & 63;
        uint2 cw;
        cw.x = cvtpk(acc[i][j][0] * scl, acc[i][j][1] * scl);
        cw.y = cvtpk(acc[i][j][2] * scl, acc[i][j][3] * scl);
        *(uint2*)(&Od[((((size_t)b*H_ + h)*S_) + s)*HD_ + hd]) = cw;
      }
  } else {                  // V (normal): lane holds 4 consecutive tokens -> V^T rows
    #pragma unroll
    for (int i = 0; i < 4; ++i)
      #pragma unroll
      for (int j = 0; j < 4; ++j) {
        int t0 = arow + wm*64 + i*16 + g*4;
        int f  = (brow & 1023) + wn*64 + j*16 + r16;
        int b = t0 >> 11, s = t0 & 2047, h = f >> 6, hd = f & 63;
        uint2 cw;
        cw.x = cvtpk(acc[i][j][0], acc[i][j][1]);
        cw.y = cvtpk(acc[i][j][2], acc[i][j][3]);
        *(uint2*)(&OV[(((size_t)b*H_ + h)*HD_ + hd)*S_ + s]) = cw;
      }
  }
}

// ---------------- out-proj GEMM, same 512-thr 256x128 geometry -------------
// A[8192][1024] x Wo[1024][1024]^T -> fp32 [8192][1024]. 256 blocks
// (32 bm2 x 8 bn). Swapped operands; float4 stores.
__global__ __launch_bounds__(512) void gemm_o(
    const unsigned short* __restrict__ A,
    const unsigned short* __restrict__ W,
    float* __restrict__ OF)
{
  const int tid  = threadIdx.x;
  const int lane = tid & 63;
  const int w    = tid >> 6;          // 0..7
  const int wm   = w >> 1, wn = w & 1;
  const int r16  = lane & 15, g = lane >> 4;

  // XCD-grouping swizzle over 256 blocks: XCD x owns bm2 in {4x..4x+3}.
  const int orig = blockIdx.x;
  const int bm2  = (orig & 7) * 4 + ((orig >> 3) & 3);
  const int bn   = orig >> 5;                        // 0..7

  __shared__ unsigned short As[2][8192];   // 256x32
  __shared__ unsigned short Bs[2][4096];   // 128x32

  const int arow = bm2 * 256, brow = bn * 128;
  const int srow = lane >> 2;
  const int scol  = ((lane & 3) ^ ((lane >> 3) & 3)) * 8;
  const int rslot = (g ^ ((r16 >> 1) & 3)) * 8;

  f32x4 acc[4][4] = {};
  QSTG(0, 0);
  QLOOP(true)

  #pragma unroll
  for (int i = 0; i < 4; ++i)
    #pragma unroll
    for (int j = 0; j < 4; ++j) {
      int t = arow + wm*64 + i*16 + r16;
      int f = brow + wn*64 + j*16 + g*4;
      float4 st;
      st.x = acc[i][j][0]; st.y = acc[i][j][1];
      st.z = acc[i][j][2]; st.w = acc[i][j][3];
      *(float4*)(&OF[(size_t)t * 1024 + f]) = st;
    }
}

// ---------------- flash attention, causal (R17-frozen) ---------------------
#define ASTG(BF, KB) { \
    gll16(Kh + (size_t)((KB) + tr0 +     rsub)*HD_ + csw, &KVb[BF][0][ tr0     *64]); \
    gll16(Kh + (size_t)((KB) + tr0 + 8 + rsub)*HD_ + csw, &KVb[BF][0][(tr0 + 8)*64]); \
    gll16(Vh + (size_t)(tr0 +     rsub)*S_ + (KB) + csw,  &KVb[BF][1][ tr0     *64]); \
    gll16(Vh + (size_t)(tr0 + 8 + rsub)*S_ + (KB) + csw,  &KVb[BF][1][(tr0 + 8)*64]); }

#define ACOMP2(BF, KB) { \
    const int kb_ = (KB); \
    if (kb_ <= qw + 31) { \
      f32x4 sc[2][4]; \
      __builtin_amdgcn_s_setprio(1); \
      _Pragma("unroll") for (int c = 0; c < 4; ++c) { \
        bf16x8 kf0 = *(const bf16x8*)((const char*)&KVb[BF][0][0] + (c*16 + r16)*128 + ((( g      ^ (r16 & 7)) & 7) << 4)); \
        bf16x8 kf1 = *(const bf16x8*)((const char*)&KVb[BF][0][0] + (c*16 + r16)*128 + ((((4 + g) ^ (r16 & 7)) & 7) << 4)); \
        _Pragma("unroll") for (int qi = 0; qi < 2; ++qi) { \
          f32x4 s_ = {}; \
          s_ = MFMA16(kf0, qf[qi][0], s_, 0, 0, 0); \
          s_ = MFMA16(kf1, qf[qi][1], s_, 0, 0, 0); \
          sc[qi][c] = s_; } } \
      __builtin_amdgcn_s_setprio(0); \
      _Pragma("unroll") for (int qi = 0; qi < 2; ++qi) { \
        f32x4 p4[4]; \
        if (kb_ + 63 > qw + qi*16) { \
          const int qrow_ = qw + qi*16 + r16; \
          _Pragma("unroll") for (int c = 0; c < 4; ++c) \
            _Pragma("unroll") for (int r = 0; r < 4; ++r) \
              p4[c][r] = (kb_ + c*16 + g*4 + r > qrow_) ? 0.f : exp2f(sc[qi][c][r]); \
        } else { \
          _Pragma("unroll") for (int c = 0; c < 4; ++c) \
            _Pragma("unroll") for (int r = 0; r < 4; ++r) \
              p4[c][r] = exp2f(sc[qi][c][r]); } \
        char* prp_ = Plw + (qi*16 + r16)*128; \
        const int swz_ = (r16 & 7) << 4; \
        _Pragma("unroll") for (int c = 0; c < 4; ++c) { \
          uint2 pw_; \
          pw_.x = cvtpk(p4[c][0], p4[c][1]); \
          pw_.y = cvtpk(p4[c][2], p4[c][3]); \
          *(uint2*)(prp_ + ((c*32 + g*8) ^ swz_)) = pw_; } } \
      __builtin_amdgcn_s_setprio(1); \
      _Pragma("unroll") for (int kc = 0; kc < 2; ++kc) { \
        bf16x8 pf0_ = *(const bf16x8*)(Plw + r16*128        + ((kc*64 + g*16) ^ ((r16 & 7) << 4))); \
        bf16x8 pf1_ = *(const bf16x8*)(Plw + (16 + r16)*128 + ((kc*64 + g*16) ^ ((r16 & 7) << 4))); \
        oL[0] = MFMA16(onesf, pf0_, oL[0], 0, 0, 0); \
        oL[1] = MFMA16(onesf, pf1_, oL[1], 0, 0, 0); \
        _Pragma("unroll") for (int dn = 0; dn < 4; ++dn) { \
          bf16x8 vf_ = *(const bf16x8*)((const char*)&KVb[BF][1][0] + (dn*16 + r16)*128 + ((((kc*4 + g) ^ (r16 & 7)) & 7) << 4)); \
          oT[0][dn] = MFMA16(vf_, pf0_, oT[0][dn], 0, 0, 0); \
          oT[1][dn] = MFMA16(vf_, pf1_, oT[1][dn], 0, 0, 0); } } \
      __builtin_amdgcn_s_setprio(0); \
    } }

__global__ __launch_bounds__(256, 3) void attn_fwd(
    const unsigned short* __restrict__ Q,
    const unsigned short* __restrict__ K,
    const unsigned short* __restrict__ Vt,
    unsigned short* __restrict__ C)
{
  const int tid  = threadIdx.x;
  const int lane = tid & 63;
  const int w    = tid >> 6;
  const int r16  = lane & 15, g = lane >> 4;

  const int l_   = blockIdx.x;
  const int bh   = (l_ & 7) * 8 + ((l_ >> 3) & 7);   // 8 heads per XCD
  const int jt   = 15 - (l_ >> 6);                   // 128-row q-tile, longest first
  const int bb   = bh >> 4, hh = bh & 15;

  const unsigned short* Qh = Q  + (size_t)bh * S_ * HD_;
  const unsigned short* Kh = K  + (size_t)bh * S_ * HD_;
  const unsigned short* Vh = Vt + (size_t)bh * HD_ * S_;   // [64 hd][2048 k]

  __shared__ unsigned short KVb[2][2][4096];  // [buf][K/V][64x64] linear, 32KB
  __shared__ unsigned short Pl[4][2048];      // per-wave P[32][64], swizzled, 16KB
  char* Plw = (char*)&Pl[w][0];

  const int rsub = lane >> 3;                 // 0..7
  const int csw  = ((lane & 7) ^ rsub) * 8;   // pre-swizzled col (elems)
  const int tr0  = w * 16;

  bf16x8 onesf;
  #pragma unroll
  for (int j = 0; j < 8; ++j) onesf[j] = (short)0x3F80;   // bf16 1.0

  const int q0 = jt * 128;
  const int qw = q0 + w * 32;
  const int nt = 2 * jt + 2;                  // even

  bf16x8 qf[2][2];
  #pragma unroll
  for (int qi = 0; qi < 2; ++qi)
    #pragma unroll
    for (int dh = 0; dh < 2; ++dh)
      qf[qi][dh] = *(const bf16x8*)(&Qh[(size_t)(qw + qi*16 + r16) * HD_ + dh*32 + g*8]);

  f32x4 oT[2][4] = {};
  f32x4 oL[2] = {};

  ASTG(0, 0);

  for (int kt = 0; kt < nt; kt += 2) {
    __syncthreads();                          // tile kt landed for all waves
    ASTG(1, (kt + 1) * 64);
    ACOMP2(0, kt * 64);
    __syncthreads();                          // tile kt+1 landed
    if (kt + 2 < nt) ASTG(0, (kt + 2) * 64);
    ACOMP2(1, (kt + 1) * 64);
  }

  // ---- epilogue: inv = 1/l (every lane holds full sum), packed store ----
  #pragma unroll
  for (int qi = 0; qi < 2; ++qi) {
    float inv = 1.0f / oL[qi][0];
    int tok = bb * S_ + qw + qi*16 + r16;
    #pragma unroll
    for (int dn = 0; dn < 4; ++dn) {
      uint2 cw;
      cw.x = cvtpk(oT[qi][dn][0] * inv, oT[qi][dn][1] * inv);
      cw.y = cvtpk(oT[qi][dn][2] * inv, oT[qi][dn][3] * inv);
      *(uint2*)(&C[(size_t)tok * D_ + hh*HD_ + dn*16 + g*4]) = cw;
    }
  }
}

// ---------------- launch ------------------------------------------------
extern "C" void kernel_launch(void* const* d_in, const int* in_sizes, int n_in,
                              void* d_out, int out_size, void* d_ws, size_t ws_size,
                              hipStream_t stream) {
  const float* x  = (const float*)d_in[0];
  const float* Wq = (const float*)d_in[1];
  const float* Wk = (const float*)d_in[2];
  const float* Wv = (const float*)d_in[3];
  const float* Wo = (const float*)d_in[4];

  char* ws = (char*)d_ws;
  unsigned short* xb  = (unsigned short*)(ws);              // 16 MiB
  unsigned short* Wqb = (unsigned short*)(ws + 16777216);   // W3 = [Wq;Wk;Wv]
  unsigned short* Wkb = (unsigned short*)(ws + 18874368);
  unsigned short* Wvb = (unsigned short*)(ws + 20971520);
  unsigned short* Wob = (unsigned short*)(ws + 23068672);
  unsigned short* Qb  = (unsigned short*)(ws + 25165824);   // [b][h][s][hd] scaled
  unsigned short* Kb  = (unsigned short*)(ws + 41943040);   // [b][h][s][hd]
  unsigned short* Vtb = (unsigned short*)(ws + 58720256);   // [b][h][hd][s]
  unsigned short* Cb  = (unsigned short*)(ws + 75497472);   // ctx [b][s][1024]

  cvt_all<<<dim3(1024, 12), 256, 0, stream>>>(
      (const float4*)x, (const float4*)Wq, (const float4*)Wk,
      (const float4*)Wv, (const float4*)Wo,
      (ushort4*)xb, (ushort4*)Wqb, (ushort4*)Wkb, (ushort4*)Wvb, (ushort4*)Wob);

  gemm_qkv<<<768, 512, 0, stream>>>(xb, Wqb, Qb, Kb, Vtb);
  attn_fwd<<<1024, 256, 0, stream>>>(Qb, Kb, Vtb, Cb);
  gemm_o<<<256, 512, 0, stream>>>(Cb, Wob, (float*)d_out);
}

// Round 22
// 166.494 us; speedup vs baseline: 1.0207x; 1.0207x over previous
//
#include <hip/hip_runtime.h>

// Self-attention: x(4,2048,1024) fp32; W_Q/K/V/O (1024,1024) fp32.
// CONVERGED configuration (R20 = 167.0 us, best of 21 rounds):
//   - QKV GEMM: 512-thr 256x128 blocks, 3 blocks/CU (-25% stage issue, -50%
//     barriers/MFMA vs 128^2; 670 TF)
//   - out-proj: 2-phase 256-thr 128^2, 2 blocks/CU (cross-block drain overlap;
//     512-thr/1-block-CU variant measured WORSE, R21)
//   - flash attention: fixed-zero-max softmax, l-via-ones-MFMA, XOR-swizzled
//     LDS, 32 q-rows/wave, XCD-pinned heads (R17-frozen)
// Falsified: M-fusion (spill), 8-phase port (half-GPU V), 3-buffer prefetch
// (occupancy), forced launch_bounds (spill), Pl-shrink (neutral), balanced
// 1024-grid (empty tail), 512-thr out-proj (1 blk/CU).

#define B_  4
#define S_  2048
#define D_  1024
#define H_  16
#define HD_ 64

typedef __attribute__((ext_vector_type(8))) short bf16x8;
typedef __attribute__((ext_vector_type(4))) float f32x4;

#define MFMA16 __builtin_amdgcn_mfma_f32_16x16x32_bf16

__device__ __forceinline__ unsigned short f2b(float f) {
  unsigned u = __builtin_bit_cast(unsigned, f);
  unsigned r = (u + 0x7FFFu + ((u >> 16) & 1u)) >> 16;  // RNE
  return (unsigned short)r;
}

__device__ __forceinline__ unsigned cvtpk(float lo, float hi) {
  unsigned r;
  asm("v_cvt_pk_bf16_f32 %0, %1, %2" : "=v"(r) : "v"(lo), "v"(hi));
  return r;
}

// async global->LDS, 16B per lane. LDS dest must be wave-uniform base.
__device__ __forceinline__ void gll16(const void* g, const void* l) {
  __builtin_amdgcn_global_load_lds(
      (const __attribute__((address_space(1))) unsigned int*)g,
      (__attribute__((address_space(3))) unsigned int*)l, 16, 0, 0);
}

// ---------------- fp32 -> bf16 conversion (all 5 tensors, 1 launch) -------
__global__ __launch_bounds__(256) void cvt_all(
    const float4* __restrict__ x,  const float4* __restrict__ wq,
    const float4* __restrict__ wk, const float4* __restrict__ wv,
    const float4* __restrict__ wo,
    ushort4* __restrict__ xb,  ushort4* __restrict__ wqb,
    ushort4* __restrict__ wkb, ushort4* __restrict__ wvb,
    ushort4* __restrict__ wob)
{
  const int y = blockIdx.y;
  const float4* in; ushort4* out;
  if (y < 8)       { in = x  + (size_t)y * 262144; out = xb  + (size_t)y * 262144; }
  else if (y == 8) { in = wq; out = wqb; }
  else if (y == 9) { in = wk; out = wkb; }
  else if (y == 10){ in = wv; out = wvb; }
  else             { in = wo; out = wob; }
  int i = blockIdx.x * 256 + threadIdx.x;
  float4 v = in[i];
  ushort4 o;
  o.x = f2b(v.x); o.y = f2b(v.y); o.z = f2b(v.z); o.w = f2b(v.w);
  out[i] = o;
}

// ---------------- fused QKV GEMM, 512-thr 256x128 tiles --------------------
// A[8192][1024] x W3[3072][1024]^T. 768 blocks (32 bm2 x 24 bn). 8 waves:
// wm = w>>1 (4 x 64 rows), wn = w&1 (2 x 64 cols), 64x64 wave tile. bn<8 ->
// Q (swapped, scaled); bn<16 -> K (swapped); else V (normal -> V^T).
// T2 slot-swizzle: src slot ^= (lane>>3)&3 (== (row>>1)&3; wave-row base
// contributes 0); read slot = g ^ ((r16>>1)&3). LDS 48KB -> 3 blocks/CU.
#define QSTG(BF, K0) { \
    gll16(A + (size_t)(arow +       w*16 + srow)*1024 + (K0) + scol, &As[BF][        w*512]); \
    gll16(A + (size_t)(arow + 128 + w*16 + srow)*1024 + (K0) + scol, &As[BF][4096 + w*512]); \
    gll16(W + (size_t)(brow +       w*16 + srow)*1024 + (K0) + scol, &Bs[BF][        w*512]); }

#define QSTEP(BF, SW) { \
    bf16x8 af[4], bfr[4]; \
    _Pragma("unroll") for (int i = 0; i < 4; ++i) \
      af[i]  = *(const bf16x8*)(&As[BF][(wm*64 + i*16 + r16)*32 + rslot]); \
    _Pragma("unroll") for (int i = 0; i < 4; ++i) \
      bfr[i] = *(const bf16x8*)(&Bs[BF][(wn*64 + i*16 + r16)*32 + rslot]); \
    _Pragma("unroll") for (int i = 0; i < 4; ++i) \
      _Pragma("unroll") for (int j = 0; j < 4; ++j) \
        acc[i][j] = (SW) ? MFMA16(bfr[j], af[i], acc[i][j], 0, 0, 0) \
                         : MFMA16(af[i], bfr[j], acc[i][j], 0, 0, 0); }

#define QLOOP(SW) \
  for (int kt = 0; kt < 32; kt += 2) { \
    __syncthreads(); \
    QSTG(1, (kt + 1) * 32); \
    QSTEP(0, SW); \
    __syncthreads(); \
    if (kt + 2 < 32) QSTG(0, (kt + 2) * 32); \
    QSTEP(1, SW); \
  }

__global__ __launch_bounds__(512) void gemm_qkv(
    const unsigned short* __restrict__ A,
    const unsigned short* __restrict__ W,
    unsigned short* __restrict__ OQ,
    unsigned short* __restrict__ OK,
    unsigned short* __restrict__ OV)
{
  const int tid  = threadIdx.x;
  const int lane = tid & 63;
  const int w    = tid >> 6;          // 0..7
  const int wm   = w >> 1, wn = w & 1;
  const int r16  = lane & 15, g = lane >> 4;

  // XCD-grouping swizzle over 768 blocks: XCD x owns bm2 in {4x..4x+3}.
  const int orig = blockIdx.x;
  const int bm2  = (orig & 7) * 4 + ((orig >> 3) & 3);
  const int bn   = orig >> 5;                        // 0..23

  __shared__ unsigned short As[2][8192];   // 256x32
  __shared__ unsigned short Bs[2][4096];   // 128x32

  const int arow = bm2 * 256, brow = bn * 128;
  const int srow = lane >> 2;
  const int scol  = ((lane & 3) ^ ((lane >> 3) & 3)) * 8;
  const int rslot = (g ^ ((r16 >> 1) & 3)) * 8;

  f32x4 acc[4][4] = {};
  const bool vblk = (bn >= 16);
  QSTG(0, 0);
  if (!vblk) { QLOOP(true) } else { QLOOP(false) }

  if (!vblk) {              // Q or K (swapped): lane holds 4 consecutive features
    unsigned short* Od = (bn < 8) ? OQ : OK;
    const float scl = (bn < 8) ? 0.18033688f : 1.0f;   // 0.125*log2(e)
    #pragma unroll
    for (int i = 0; i < 4; ++i)
      #pragma unroll
      for (int j = 0; j < 4; ++j) {
        int t = arow + wm*64 + i*16 + r16;
        int f = (brow & 1023) + wn*64 + j*16 + g*4;
        int b = t >> 11, s = t & 2047, h = f >> 6, hd = f & 63;
        uint2 cw;
        cw.x = cvtpk(acc[i][j][0] * scl, acc[i][j][1] * scl);
        cw.y = cvtpk(acc[i][j][2] * scl, acc[i][j][3] * scl);
        *(uint2*)(&Od[((((size_t)b*H_ + h)*S_) + s)*HD_ + hd]) = cw;
      }
  } else {                  // V (normal): lane holds 4 consecutive tokens -> V^T rows
    #pragma unroll
    for (int i = 0; i < 4; ++i)
      #pragma unroll
      for (int j = 0; j < 4; ++j) {
        int t0 = arow + wm*64 + i*16 + g*4;
        int f  = (brow & 1023) + wn*64 + j*16 + r16;
        int b = t0 >> 11, s = t0 & 2047, h = f >> 6, hd = f & 63;
        uint2 cw;
        cw.x = cvtpk(acc[i][j][0], acc[i][j][1]);
        cw.y = cvtpk(acc[i][j][2], acc[i][j][3]);
        *(uint2*)(&OV[(((size_t)b*H_ + h)*HD_ + hd)*S_ + s]) = cw;
      }
  }
}

// ---------------- out-proj GEMM (2-phase 128x128, 2 blocks/CU) -------------
#define GSTG(BF, K0) { \
    _Pragma("unroll") for (int t = 0; t < 2; ++t) { \
      const int grow_ = t*64 + w*16 + srow; \
      const int lbas_ = (t*256 + w*64) * 8; \
      gll16(A + (size_t)(arow + grow_)*1024 + (K0) + scol, &As[BF][lbas_]); \
      gll16(W + (size_t)(brow + grow_)*1024 + (K0) + scol, &Bs[BF][lbas_]); } }

#define GSTEP(BF) { \
    bf16x8 af[4], bfr[4]; \
    _Pragma("unroll") for (int i = 0; i < 4; ++i) \
      af[i]  = *(const bf16x8*)(&As[BF][(wm*64 + i*16 + r16)*32 + rslot]); \
    _Pragma("unroll") for (int i = 0; i < 4; ++i) \
      bfr[i] = *(const bf16x8*)(&Bs[BF][(wn*64 + i*16 + r16)*32 + rslot]); \
    _Pragma("unroll") for (int i = 0; i < 4; ++i) \
      _Pragma("unroll") for (int j = 0; j < 4; ++j) \
        acc[i][j] = MFMA16(bfr[j], af[i], acc[i][j], 0, 0, 0); }

__global__ __launch_bounds__(256) void gemm_o(
    const unsigned short* __restrict__ A,
    const unsigned short* __restrict__ W,
    float* __restrict__ OF)
{
  const int tid  = threadIdx.x;
  const int lane = tid & 63;
  const int w    = tid >> 6;
  const int wm   = w >> 1, wn = w & 1;
  const int r16  = lane & 15, g = lane >> 4;

  const int orig = blockIdx.x + 64 * blockIdx.y;
  const int t_   = orig >> 3;
  const int bm   = (orig & 7) * 8 + (t_ & 7);
  const int bn   = t_ >> 3;

  __shared__ unsigned short As[2][4096];
  __shared__ unsigned short Bs[2][4096];

  const int arow = bm * 128, brow = bn * 128;
  const int srow = lane >> 2;
  const int scol  = ((lane & 3) ^ ((lane >> 3) & 3)) * 8;
  const int rslot = (g ^ ((r16 >> 1) & 3)) * 8;

  f32x4 acc[4][4] = {};
  GSTG(0, 0);
  for (int kt = 0; kt < 32; kt += 2) {
    __syncthreads();
    GSTG(1, (kt + 1) * 32);
    GSTEP(0);
    __syncthreads();
    if (kt + 2 < 32) GSTG(0, (kt + 2) * 32);
    GSTEP(1);
  }

  #pragma unroll
  for (int i = 0; i < 4; ++i)
    #pragma unroll
    for (int j = 0; j < 4; ++j) {
      int t = arow + wm*64 + i*16 + r16;
      int f = brow + wn*64 + j*16 + g*4;
      float4 st;
      st.x = acc[i][j][0]; st.y = acc[i][j][1];
      st.z = acc[i][j][2]; st.w = acc[i][j][3];
      *(float4*)(&OF[(size_t)t * 1024 + f]) = st;
    }
}

// ---------------- flash attention, causal (R17-frozen) ---------------------
#define ASTG(BF, KB) { \
    gll16(Kh + (size_t)((KB) + tr0 +     rsub)*HD_ + csw, &KVb[BF][0][ tr0     *64]); \
    gll16(Kh + (size_t)((KB) + tr0 + 8 + rsub)*HD_ + csw, &KVb[BF][0][(tr0 + 8)*64]); \
    gll16(Vh + (size_t)(tr0 +     rsub)*S_ + (KB) + csw,  &KVb[BF][1][ tr0     *64]); \
    gll16(Vh + (size_t)(tr0 + 8 + rsub)*S_ + (KB) + csw,  &KVb[BF][1][(tr0 + 8)*64]); }

#define ACOMP2(BF, KB) { \
    const int kb_ = (KB); \
    if (kb_ <= qw + 31) { \
      f32x4 sc[2][4]; \
      __builtin_amdgcn_s_setprio(1); \
      _Pragma("unroll") for (int c = 0; c < 4; ++c) { \
        bf16x8 kf0 = *(const bf16x8*)((const char*)&KVb[BF][0][0] + (c*16 + r16)*128 + ((( g      ^ (r16 & 7)) & 7) << 4)); \
        bf16x8 kf1 = *(const bf16x8*)((const char*)&KVb[BF][0][0] + (c*16 + r16)*128 + ((((4 + g) ^ (r16 & 7)) & 7) << 4)); \
        _Pragma("unroll") for (int qi = 0; qi < 2; ++qi) { \
          f32x4 s_ = {}; \
          s_ = MFMA16(kf0, qf[qi][0], s_, 0, 0, 0); \
          s_ = MFMA16(kf1, qf[qi][1], s_, 0, 0, 0); \
          sc[qi][c] = s_; } } \
      __builtin_amdgcn_s_setprio(0); \
      _Pragma("unroll") for (int qi = 0; qi < 2; ++qi) { \
        f32x4 p4[4]; \
        if (kb_ + 63 > qw + qi*16) { \
          const int qrow_ = qw + qi*16 + r16; \
          _Pragma("unroll") for (int c = 0; c < 4; ++c) \
            _Pragma("unroll") for (int r = 0; r < 4; ++r) \
              p4[c][r] = (kb_ + c*16 + g*4 + r > qrow_) ? 0.f : exp2f(sc[qi][c][r]); \
        } else { \
          _Pragma("unroll") for (int c = 0; c < 4; ++c) \
            _Pragma("unroll") for (int r = 0; r < 4; ++r) \
              p4[c][r] = exp2f(sc[qi][c][r]); } \
        char* prp_ = Plw + (qi*16 + r16)*128; \
        const int swz_ = (r16 & 7) << 4; \
        _Pragma("unroll") for (int c = 0; c < 4; ++c) { \
          uint2 pw_; \
          pw_.x = cvtpk(p4[c][0], p4[c][1]); \
          pw_.y = cvtpk(p4[c][2], p4[c][3]); \
          *(uint2*)(prp_ + ((c*32 + g*8) ^ swz_)) = pw_; } } \
      __builtin_amdgcn_s_setprio(1); \
      _Pragma("unroll") for (int kc = 0; kc < 2; ++kc) { \
        bf16x8 pf0_ = *(const bf16x8*)(Plw + r16*128        + ((kc*64 + g*16) ^ ((r16 & 7) << 4))); \
        bf16x8 pf1_ = *(const bf16x8*)(Plw + (16 + r16)*128 + ((kc*64 + g*16) ^ ((r16 & 7) << 4))); \
        oL[0] = MFMA16(onesf, pf0_, oL[0], 0, 0, 0); \
        oL[1] = MFMA16(onesf, pf1_, oL[1], 0, 0, 0); \
        _Pragma("unroll") for (int dn = 0; dn < 4; ++dn) { \
          bf16x8 vf_ = *(const bf16x8*)((const char*)&KVb[BF][1][0] + (dn*16 + r16)*128 + ((((kc*4 + g) ^ (r16 & 7)) & 7) << 4)); \
          oT[0][dn] = MFMA16(vf_, pf0_, oT[0][dn], 0, 0, 0); \
          oT[1][dn] = MFMA16(vf_, pf1_, oT[1][dn], 0, 0, 0); } } \
      __builtin_amdgcn_s_setprio(0); \
    } }

__global__ __launch_bounds__(256, 3) void attn_fwd(
    const unsigned short* __restrict__ Q,
    const unsigned short* __restrict__ K,
    const unsigned short* __restrict__ Vt,
    unsigned short* __restrict__ C)
{
  const int tid  = threadIdx.x;
  const int lane = tid & 63;
  const int w    = tid >> 6;
  const int r16  = lane & 15, g = lane >> 4;

  const int l_   = blockIdx.x;
  const int bh   = (l_ & 7) * 8 + ((l_ >> 3) & 7);   // 8 heads per XCD
  const int jt   = 15 - (l_ >> 6);                   // 128-row q-tile, longest first
  const int bb   = bh >> 4, hh = bh & 15;

  const unsigned short* Qh = Q  + (size_t)bh * S_ * HD_;
  const unsigned short* Kh = K  + (size_t)bh * S_ * HD_;
  const unsigned short* Vh = Vt + (size_t)bh * HD_ * S_;   // [64 hd][2048 k]

  __shared__ unsigned short KVb[2][2][4096];  // [buf][K/V][64x64] linear, 32KB
  __shared__ unsigned short Pl[4][2048];      // per-wave P[32][64], swizzled, 16KB
  char* Plw = (char*)&Pl[w][0];

  const int rsub = lane >> 3;                 // 0..7
  const int csw  = ((lane & 7) ^ rsub) * 8;   // pre-swizzled col (elems)
  const int tr0  = w * 16;

  bf16x8 onesf;
  #pragma unroll
  for (int j = 0; j < 8; ++j) onesf[j] = (short)0x3F80;   // bf16 1.0

  const int q0 = jt * 128;
  const int qw = q0 + w * 32;
  const int nt = 2 * jt + 2;                  // even

  bf16x8 qf[2][2];
  #pragma unroll
  for (int qi = 0; qi < 2; ++qi)
    #pragma unroll
    for (int dh = 0; dh < 2; ++dh)
      qf[qi][dh] = *(const bf16x8*)(&Qh[(size_t)(qw + qi*16 + r16) * HD_ + dh*32 + g*8]);

  f32x4 oT[2][4] = {};
  f32x4 oL[2] = {};

  ASTG(0, 0);

  for (int kt = 0; kt < nt; kt += 2) {
    __syncthreads();                          // tile kt landed for all waves
    ASTG(1, (kt + 1) * 64);
    ACOMP2(0, kt * 64);
    __syncthreads();                          // tile kt+1 landed
    if (kt + 2 < nt) ASTG(0, (kt + 2) * 64);
    ACOMP2(1, (kt + 1) * 64);
  }

  // ---- epilogue: inv = 1/l (every lane holds full sum), packed store ----
  #pragma unroll
  for (int qi = 0; qi < 2; ++qi) {
    float inv = 1.0f / oL[qi][0];
    int tok = bb * S_ + qw + qi*16 + r16;
    #pragma unroll
    for (int dn = 0; dn < 4; ++dn) {
      uint2 cw;
      cw.x = cvtpk(oT[qi][dn][0] * inv, oT[qi][dn][1] * inv);
      cw.y = cvtpk(oT[qi][dn][2] * inv, oT[qi][dn][3] * inv);
      *(uint2*)(&C[(size_t)tok * D_ + hh*HD_ + dn*16 + g*4]) = cw;
    }
  }
}

// ---------------- launch ------------------------------------------------
extern "C" void kernel_launch(void* const* d_in, const int* in_sizes, int n_in,
                              void* d_out, int out_size, void* d_ws, size_t ws_size,
                              hipStream_t stream) {
  const float* x  = (const float*)d_in[0];
  const float* Wq = (const float*)d_in[1];
  const float* Wk = (const float*)d_in[2];
  const float* Wv = (const float*)d_in[3];
  const float* Wo = (const float*)d_in[4];

  char* ws = (char*)d_ws;
  unsigned short* xb  = (unsigned short*)(ws);              // 16 MiB
  unsigned short* Wqb = (unsigned short*)(ws + 16777216);   // W3 = [Wq;Wk;Wv]
  unsigned short* Wkb = (unsigned short*)(ws + 18874368);
  unsigned short* Wvb = (unsigned short*)(ws + 20971520);
  unsigned short* Wob = (unsigned short*)(ws + 23068672);
  unsigned short* Qb  = (unsigned short*)(ws + 25165824);   // [b][h][s][hd] scaled
  unsigned short* Kb  = (unsigned short*)(ws + 41943040);   // [b][h][s][hd]
  unsigned short* Vtb = (unsigned short*)(ws + 58720256);   // [b][h][hd][s]
  unsigned short* Cb  = (unsigned short*)(ws + 75497472);   // ctx [b][s][1024]

  cvt_all<<<dim3(1024, 12), 256, 0, stream>>>(
      (const float4*)x, (const float4*)Wq, (const float4*)Wk,
      (const float4*)Wv, (const float4*)Wo,
      (ushort4*)xb, (ushort4*)Wqb, (ushort4*)Wkb, (ushort4*)Wvb, (ushort4*)Wob);

  gemm_qkv<<<768, 512, 0, stream>>>(xb, Wqb, Qb, Kb, Vtb);
  attn_fwd<<<1024, 256, 0, stream>>>(Qb, Kb, Vtb, Cb);
  gemm_o<<<dim3(64, 8), 256, 0, stream>>>(Cb, Wob, (float*)d_out);
}